// Round 4
// baseline (726.712 us; speedup 1.0000x reference)
//
#include <hip/hip_runtime.h>
#include <hip/hip_bf16.h>
#include <stdint.h>

#define N_  6144
#define T_  3072
#define D_  128
#define H_  4
#define HD_ 512

typedef float f32x4 __attribute__((ext_vector_type(4)));
typedef short s16x8 __attribute__((ext_vector_type(8)));

static __device__ __forceinline__ short f2bf(float f) {
  union { __hip_bfloat16 b; short s; } u;
  u.b = __float2bfloat16(f);
  return u.s;
}

// ---------------- adj (int32 0/1) -> bitmask ----------------
__global__ __launch_bounds__(256) void bits_kernel(const int* __restrict__ adj,
                                                   unsigned long long* __restrict__ bits,
                                                   int nwords) {
  int lane = threadIdx.x & 63;
  int gw = (blockIdx.x * blockDim.x + threadIdx.x) >> 6;
  int nw = (gridDim.x * blockDim.x) >> 6;
  for (int w = gw; w < nwords; w += nw) {
    int v = adj[(long)w * 64 + lane];
    unsigned long long b = __ballot(v != 0);
    if (lane == 0) bits[w] = b;
  }
}

// ---------------- fp32 -> bf16 (same layout) ----------------
__global__ __launch_bounds__(256) void cvt_kernel(const float* __restrict__ in,
                                                  short* __restrict__ out, int count4) {
  int i = blockIdx.x * blockDim.x + threadIdx.x;
  if (i < count4) {
    float4 v = *(const float4*)(in + (long)i * 4);
    short4 o;
    o.x = f2bf(v.x); o.y = f2bf(v.y); o.z = f2bf(v.z); o.w = f2bf(v.w);
    *(short4*)(out + (long)i * 4) = o;
  }
}

// ---------------- fp32 [R][C] -> bf16 [C][R] (batched) ----------------
__global__ __launch_bounds__(256) void tcvt_kernel(const float* __restrict__ in,
                                                   short* __restrict__ out,
                                                   int R, int C, long sIn, long sOut) {
  __shared__ float t[32][33];
  in += (long)blockIdx.z * sIn;
  out += (long)blockIdx.z * sOut;
  int c0 = blockIdx.x * 32, r0 = blockIdx.y * 32;
  int tx = threadIdx.x, ty = threadIdx.y;   // block (32,8)
#pragma unroll
  for (int i = 0; i < 4; ++i)
    t[ty + 8 * i][tx] = in[(long)(r0 + ty + 8 * i) * C + c0 + tx];
  __syncthreads();
#pragma unroll
  for (int i = 0; i < 4; ++i)
    out[(long)(c0 + ty + 8 * i) * R + r0 + tx] = f2bf(t[tx][ty + 8 * i]);
}

// ---------------- u_s[h][d] = sum_e W[h][d][e]*a_src[h][e] ----------------
__global__ void headvec_kernel(const float* __restrict__ W, const float* __restrict__ a_s,
                               const float* __restrict__ a_d, float* __restrict__ u_s,
                               float* __restrict__ u_d) {
  int h = blockIdx.x, d = threadIdx.x;
  const float* wr = W + ((long)h * D_ + d) * D_;
  const float* as = a_s + h * D_;
  const float* ad = a_d + h * D_;
  float s = 0.f, t = 0.f;
#pragma unroll 8
  for (int e = 0; e < D_; ++e) { s += wr[e] * as[e]; t += wr[e] * ad[e]; }
  u_s[h * D_ + d] = s;
  u_d[h * D_ + d] = t;
}

// ---------------- f_s/f_d (pre-scaled by log2e) ----------------
__global__ __launch_bounds__(256) void fvec_kernel(const float* __restrict__ x,
                                                   const float* __restrict__ u_s,
                                                   const float* __restrict__ u_d,
                                                   float* __restrict__ fsA,
                                                   float* __restrict__ fdA,
                                                   int n) {
  __shared__ float usl[128], udl[128];
  long idx = (long)blockIdx.x * 256 + threadIdx.x;
  int h = (int)(idx / n), i = (int)(idx % n);
  if (threadIdx.x < 128) {
    usl[threadIdx.x] = u_s[h * D_ + threadIdx.x];
    udl[threadIdx.x] = u_d[h * D_ + threadIdx.x];
  }
  __syncthreads();
  const float4* xr = (const float4*)(x + (long)i * D_);
  float s = 0.f, t = 0.f;
#pragma unroll 8
  for (int e4 = 0; e4 < 32; ++e4) {
    float4 xv = xr[e4];
    s += xv.x * usl[4 * e4] + xv.y * usl[4 * e4 + 1] + xv.z * usl[4 * e4 + 2] + xv.w * usl[4 * e4 + 3];
    t += xv.x * udl[4 * e4] + xv.y * udl[4 * e4 + 1] + xv.z * udl[4 * e4 + 2] + xv.w * udl[4 * e4 + 3];
  }
  const float L2E = 1.4426950408889634f;
  fsA[idx] = s * L2E;
  fdA[idx] = t * L2E;
}

// ---------------- generic bf16 MFMA GEMM (depth-2 prefetch, 1 barrier/iter) ----
// epi: 0 = bf16 store, 1 = fp32 relu+bias, 2 = bf16 relu+bias transposed, 3 = fp32 plain (+bz*sOut)
__global__ __launch_bounds__(256) void gemm_kernel(const short* __restrict__ A,
                                                   const short* __restrict__ BT,
                                                   int M, int K, int lda, int ldb,
                                                   float* __restrict__ outF, short* __restrict__ outB,
                                                   const float* __restrict__ bias,
                                                   int ldo, int epi,
                                                   long sA, long sBT, long sOut) {
  int bz = blockIdx.z;
  A += bz * sA;
  BT += bz * sBT;
  __shared__ __align__(16) short bs[2][4096];
  int tid = threadIdx.x, w = tid >> 6, l = tid & 63, lm = l & 15, lg = l >> 4;
  int row0 = blockIdx.x * 64 + w * 16;
  int col0 = blockIdx.y * 128;
  const short* arow = A + (long)(row0 + lm) * lda + 8 * lg;
  const short* b0 = BT + (long)(col0 + 16 * (2 * w + 0) + lm) * ldb + 8 * lg;
  const short* b1 = BT + (long)(col0 + 16 * (2 * w + 1) + lm) * ldb + 8 * lg;
  f32x4 acc[8] = {};
  int nt = K / 32;
  int4 pr0[2], pr1[2];
  s16x8 prA[2];
  pr0[0] = *(const int4*)(b0);      pr1[0] = *(const int4*)(b1);      prA[0] = *(const s16x8*)(arow);
  pr0[1] = *(const int4*)(b0 + 32); pr1[1] = *(const int4*)(b1 + 32); prA[1] = *(const s16x8*)(arow + 32);
  for (int kt = 0; kt < nt; ++kt) {
    int sl = kt & 1;
    ((int4*)bs[sl])[(2 * w + 0) * 64 + l] = pr0[sl];
    ((int4*)bs[sl])[(2 * w + 1) * 64 + l] = pr1[sl];
    s16x8 af = prA[sl];
    int kn = (kt + 2 < nt ? kt + 2 : kt) * 32;
    pr0[sl] = *(const int4*)(b0 + kn);
    pr1[sl] = *(const int4*)(b1 + kn);
    prA[sl] = *(const s16x8*)(arow + kn);
    __syncthreads();
#pragma unroll
    for (int f = 0; f < 8; ++f) {
      s16x8 bf = *(const s16x8*)(bs[sl] + f * 512 + l * 8);
      acc[f] = __builtin_amdgcn_mfma_f32_16x16x32_bf16(af, bf, acc[f], 0, 0, 0);
    }
  }
#pragma unroll
  for (int f = 0; f < 8; ++f) {
    int col = col0 + 16 * f + lm;
#pragma unroll
    for (int r = 0; r < 4; ++r) {
      int row = row0 + 4 * lg + r;
      float v = acc[f][r];
      if (epi == 0) {
        outB[bz * sOut + (long)row * ldo + col] = f2bf(v);
      } else if (epi == 1) {
        v += bias[col]; v = v > 0.f ? v : 0.f;
        outF[(long)row * ldo + col] = v;
      } else if (epi == 2) {
        v += bias[col]; v = v > 0.f ? v : 0.f;
        outB[(long)col * ldo + row] = f2bf(v);
      } else {
        outF[bz * sOut + (long)row * ldo + col] = v;
      }
    }
  }
}

// ---------------- fused masked-softmax attention, barrier-free main loop ----
// grid (n/32, H), block 256 (4 waves). Wave w handles k-chunks {w, w+4, ...}
// reading B-fragments directly from global (L2-resident WhT). One LDS
// reduction at the end merges wave partials, applies 1/Z + ELU, writes hcat.
__global__ __launch_bounds__(256) void attn_kernel(const short* __restrict__ WhT,
                                                   const unsigned char* __restrict__ bits,
                                                   const float* __restrict__ fsA,
                                                   const float* __restrict__ fdA,
                                                   short* __restrict__ hcat,
                                                   int n) {
  int h = blockIdx.y;
  const short* whT = WhT + (long)h * D_ * n;
  const float* fa = fdA + (long)h * n;
  __shared__ float red[32 * 128 + 32];
  int tid = threadIdx.x, w = tid >> 6, l = tid & 63, lm = l & 15, lg = l >> 4;
  int i0 = blockIdx.x * 32;
  int irow0 = i0 + lm;
  int irow1 = i0 + 16 + lm;
  float fs0 = fsA[(long)h * n + irow0];
  float fs1 = fsA[(long)h * n + irow1];
  const unsigned char* brow0 = bits + (long)irow0 * (n >> 3);
  const unsigned char* brow1 = bits + (long)irow1 * (n >> 3);
  const short* wrow = whT + (long)lm * n + 8 * lg;
  f32x4 acc0[8] = {}, acc1[8] = {};
  float z0 = 0.f, z1 = 0.f;
  int nt = n / 32;
  for (int kt = w; kt < nt; kt += 4) {
    int kb = kt * 32;
    // B fragments straight from global (16 rows x 64B pattern, L2-resident)
    s16x8 bf[8];
#pragma unroll
    for (int f = 0; f < 8; ++f)
      bf[f] = *(const s16x8*)(wrow + kb + (long)(16 * f) * n);
    // per-row mask dword (broadcast across lg), f_d values (broadcast)
    unsigned mw0 = *(const unsigned*)(brow0 + 4 * kt);
    unsigned mw1 = *(const unsigned*)(brow1 + 4 * kt);
    unsigned mb0 = mw0 >> (8 * lg);
    unsigned mb1 = mw1 >> (8 * lg);
    float fav[8];
    *(float4*)(fav) = *(const float4*)(fa + kb + 8 * lg);
    *(float4*)(fav + 4) = *(const float4*)(fa + kb + 8 * lg + 4);
    union { s16x8 v; unsigned u[4]; } af0, af1;
#pragma unroll
    for (int jj = 0; jj < 4; ++jj) {
      float x0 = fav[2 * jj], x1 = fav[2 * jj + 1];
      float ua = fs0 + x0, ub = fs0 + x1;
      ua = ((mb0 >> (2 * jj)) & 1u) ? ua : -1e30f;
      ub = ((mb0 >> (2 * jj + 1)) & 1u) ? ub : -1e30f;
      float pa = __builtin_amdgcn_exp2f(fmaxf(ua, 0.2f * ua));
      float pb = __builtin_amdgcn_exp2f(fmaxf(ub, 0.2f * ub));
      z0 += pa + pb;
      unsigned ba = __float_as_uint(pa) + 0x8000u;
      unsigned bb = __float_as_uint(pb) + 0x8000u;
      af0.u[jj] = __builtin_amdgcn_perm(bb, ba, 0x07060302);
      ua = fs1 + x0; ub = fs1 + x1;
      ua = ((mb1 >> (2 * jj)) & 1u) ? ua : -1e30f;
      ub = ((mb1 >> (2 * jj + 1)) & 1u) ? ub : -1e30f;
      pa = __builtin_amdgcn_exp2f(fmaxf(ua, 0.2f * ua));
      pb = __builtin_amdgcn_exp2f(fmaxf(ub, 0.2f * ub));
      z1 += pa + pb;
      ba = __float_as_uint(pa) + 0x8000u;
      bb = __float_as_uint(pb) + 0x8000u;
      af1.u[jj] = __builtin_amdgcn_perm(bb, ba, 0x07060302);
    }
#pragma unroll
    for (int f = 0; f < 8; ++f) {
      acc0[f] = __builtin_amdgcn_mfma_f32_16x16x32_bf16(af0.v, bf[f], acc0[f], 0, 0, 0);
      acc1[f] = __builtin_amdgcn_mfma_f32_16x16x32_bf16(af1.v, bf[f], acc1[f], 0, 0, 0);
    }
  }
  // wave-local Z over k-groups (lanes sharing lm)
  z0 += __shfl_xor(z0, 16); z0 += __shfl_xor(z0, 32);
  z1 += __shfl_xor(z1, 16); z1 += __shfl_xor(z1, 32);
  // zero LDS, then cross-wave reduce via LDS atomics
  for (int i = tid; i < 32 * 128 + 32; i += 256) red[i] = 0.f;
  __syncthreads();
  float* zr = red + 32 * 128;
#pragma unroll
  for (int f = 0; f < 8; ++f) {
#pragma unroll
    for (int r = 0; r < 4; ++r) {
      atomicAdd(&red[(4 * lg + r) * 128 + 16 * f + lm], acc0[f][r]);
      atomicAdd(&red[(16 + 4 * lg + r) * 128 + 16 * f + lm], acc1[f][r]);
    }
  }
  if (l < 16) {
    atomicAdd(&zr[lm], z0);
    atomicAdd(&zr[16 + lm], z1);
  }
  __syncthreads();
  // epilogue: 1/Z, elu, bf16 pack, row-major coalesced store
  int row = tid >> 3;
  int c0 = (tid & 7) * 16;
  float iz = 1.f / zr[row];
  short* orow = hcat + (long)(i0 + row) * HD_ + h * D_ + c0;
#pragma unroll
  for (int c = 0; c < 4; ++c) {
    f32x4 v = *(const f32x4*)&red[row * 128 + c0 + 4 * c];
    short4 o;
    float t;
    t = v[0] * iz; o.x = f2bf(t > 0.f ? t : __expf(t) - 1.f);
    t = v[1] * iz; o.y = f2bf(t > 0.f ? t : __expf(t) - 1.f);
    t = v[2] * iz; o.z = f2bf(t > 0.f ? t : __expf(t) - 1.f);
    t = v[3] * iz; o.w = f2bf(t > 0.f ? t : __expf(t) - 1.f);
    *(short4*)(orow + 4 * c) = o;
  }
}

// ---------------- gated fusion (ctext from Sc partials) + final GEMM + relu ----------------
__global__ __launch_bounds__(256) void fusion_kernel(const float* __restrict__ concept,
                                                     const float* __restrict__ ctextP,
                                                     int Sc, long sCt,
                                                     const short* __restrict__ fusT,
                                                     const float* __restrict__ fus_b,
                                                     float* __restrict__ out) {
  __shared__ __align__(16) short als[64 * 136];
  int tid = threadIdx.x;
  int r0 = blockIdx.x * 64;
#pragma unroll
  for (int it = 0; it < 8; ++it) {
    int e = it * 1024 + tid * 4;
    int r = e >> 7, c = e & 127;
    float4 cv = *(const float4*)(concept + (long)(r0 + r) * D_ + c);
    f32x4 tv = {};
    for (int s = 0; s < Sc; ++s)
      tv += *(const f32x4*)(ctextP + (long)s * sCt + (long)(r0 + r) * D_ + c);
    short4 o;
    {
      float s0 = cv.x + tv[0]; float z = 1.f / (1.f + __expf(-s0)); o.x = f2bf(tv[0] + z * (cv.x - tv[0]));
      s0 = cv.y + tv[1]; z = 1.f / (1.f + __expf(-s0)); o.y = f2bf(tv[1] + z * (cv.y - tv[1]));
      s0 = cv.z + tv[2]; z = 1.f / (1.f + __expf(-s0)); o.z = f2bf(tv[2] + z * (cv.z - tv[2]));
      s0 = cv.w + tv[3]; z = 1.f / (1.f + __expf(-s0)); o.w = f2bf(tv[3] + z * (cv.w - tv[3]));
    }
    *(short4*)(als + (long)r * 136 + c) = o;
  }
  __syncthreads();
  int w = tid >> 6, l = tid & 63, lm = l & 15, lg = l >> 4;
  f32x4 acc[8] = {};
#pragma unroll
  for (int kt = 0; kt < 4; ++kt) {
    int kb = kt * 32;
    s16x8 af = *(const s16x8*)(als + (16 * w + lm) * 136 + kb + 8 * lg);
#pragma unroll
    for (int f = 0; f < 8; ++f) {
      s16x8 bf = *(const s16x8*)(fusT + (long)(16 * f + lm) * D_ + kb + 8 * lg);
      acc[f] = __builtin_amdgcn_mfma_f32_16x16x32_bf16(af, bf, acc[f], 0, 0, 0);
    }
  }
#pragma unroll
  for (int f = 0; f < 8; ++f) {
    int col = 16 * f + lm;
#pragma unroll
    for (int r = 0; r < 4; ++r) {
      float v = acc[f][r] + fus_b[col];
      v = v > 0.f ? v : 0.f;
      out[(long)(r0 + 16 * w + 4 * lg + r) * D_ + col] = v;
    }
  }
}

extern "C" void kernel_launch(void* const* d_in, const int* in_sizes, int n_in,
                              void* d_out, int out_size, void* d_ws, size_t ws_size,
                              hipStream_t stream) {
  (void)in_sizes; (void)n_in; (void)out_size;
  const float* x      = (const float*)d_in[0];
  const int*   adj    = (const int*)d_in[1];
  const float* t_x    = (const float*)d_in[2];
  const int*   t_adj  = (const int*)d_in[3];
  const float* tfidf  = (const float*)d_in[4];
  const float* Wg     = (const float*)d_in[5];
  const float* ag_src = (const float*)d_in[6];
  const float* ag_dst = (const float*)d_in[7];
  const float* fcg_W  = (const float*)d_in[8];
  const float* fcg_b  = (const float*)d_in[9];
  const float* Wt     = (const float*)d_in[10];
  const float* at_src = (const float*)d_in[11];
  const float* at_dst = (const float*)d_in[12];
  const float* fct_W  = (const float*)d_in[13];
  const float* fct_b  = (const float*)d_in[14];
  const float* fus_W  = (const float*)d_in[15];
  const float* fus_b  = (const float*)d_in[16];
  float* out = (float*)d_out;

  char* ws = (char*)d_ws;
  size_t off = 0;
  auto alloc = [&](size_t bytes) -> char* {
    char* p = ws + off;
    off = (off + bytes + 255) & ~(size_t)255;
    return p;
  };
  unsigned long long* bitsG = (unsigned long long*)alloc((size_t)N_ * N_ / 8);
  unsigned long long* bitsT = (unsigned long long*)alloc((size_t)T_ * T_ / 8);
  short* xb     = (short*)alloc((size_t)N_ * D_ * 2);
  short* txb    = (short*)alloc((size_t)T_ * D_ * 2);
  short* WgT    = (short*)alloc((size_t)H_ * D_ * D_ * 2);
  short* WtT    = (short*)alloc((size_t)H_ * D_ * D_ * 2);
  short* fcgT   = (short*)alloc((size_t)HD_ * D_ * 2);
  short* fctT   = (short*)alloc((size_t)HD_ * D_ * 2);
  short* fusT   = (short*)alloc((size_t)D_ * D_ * 2);
  short* tfidfT = (short*)alloc((size_t)N_ * T_ * 2);
  short* WhTg   = (short*)alloc((size_t)H_ * D_ * N_ * 2);
  short* WhTt   = (short*)alloc((size_t)H_ * D_ * T_ * 2);
  float* usG = (float*)alloc(H_ * D_ * 4);
  float* udG = (float*)alloc(H_ * D_ * 4);
  float* usT = (float*)alloc(H_ * D_ * 4);
  float* udT = (float*)alloc(H_ * D_ * 4);
  float* fsAg = (float*)alloc((size_t)H_ * N_ * 4);
  float* fdAg = (float*)alloc((size_t)H_ * N_ * 4);
  float* fsAt = (float*)alloc((size_t)H_ * T_ * 4);
  float* fdAt = (float*)alloc((size_t)H_ * T_ * 4);
  short* hcatG = (short*)alloc((size_t)N_ * HD_ * 2);
  short* hcatT = (short*)alloc((size_t)T_ * HD_ * 2);
  short* gatT  = (short*)alloc((size_t)D_ * T_ * 2);
  float* conceptF = (float*)alloc((size_t)N_ * D_ * 4);

  const size_t ctp1 = (size_t)N_ * D_ * 4;
  size_t rem = (ws_size > off + (1 << 20)) ? (ws_size - off - (1 << 20)) : 0;
  int Sc = 1;
  if (rem >= 4 * ctp1) Sc = 4;
  else if (rem >= 2 * ctp1) Sc = 2;
  float* ctextP = (float*)alloc(Sc * ctp1);

  // --- prep ---
  bits_kernel<<<dim3(1024), dim3(256), 0, stream>>>(adj, bitsG, N_ * N_ / 64);
  bits_kernel<<<dim3(512), dim3(256), 0, stream>>>(t_adj, bitsT, T_ * T_ / 64);
  cvt_kernel<<<dim3(N_ * D_ / 1024), dim3(256), 0, stream>>>(x, xb, N_ * D_ / 4);
  cvt_kernel<<<dim3(T_ * D_ / 1024), dim3(256), 0, stream>>>(t_x, txb, T_ * D_ / 4);
  tcvt_kernel<<<dim3(4, 4, 4), dim3(32, 8), 0, stream>>>(Wg, WgT, D_, D_, (long)D_ * D_, (long)D_ * D_);
  tcvt_kernel<<<dim3(4, 4, 4), dim3(32, 8), 0, stream>>>(Wt, WtT, D_, D_, (long)D_ * D_, (long)D_ * D_);
  tcvt_kernel<<<dim3(4, 16, 1), dim3(32, 8), 0, stream>>>(fcg_W, fcgT, HD_, D_, 0, 0);
  tcvt_kernel<<<dim3(4, 16, 1), dim3(32, 8), 0, stream>>>(fct_W, fctT, HD_, D_, 0, 0);
  tcvt_kernel<<<dim3(4, 4, 1), dim3(32, 8), 0, stream>>>(fus_W, fusT, D_, D_, 0, 0);
  tcvt_kernel<<<dim3(N_ / 32, T_ / 32, 1), dim3(32, 8), 0, stream>>>(tfidf, tfidfT, T_, N_, 0, 0);
  headvec_kernel<<<dim3(H_), dim3(128), 0, stream>>>(Wg, ag_src, ag_dst, usG, udG);
  headvec_kernel<<<dim3(H_), dim3(128), 0, stream>>>(Wt, at_src, at_dst, usT, udT);
  fvec_kernel<<<dim3(H_ * N_ / 256), dim3(256), 0, stream>>>(x, usG, udG, fsAg, fdAg, N_);
  fvec_kernel<<<dim3(H_ * T_ / 256), dim3(256), 0, stream>>>(t_x, usT, udT, fsAt, fdAt, T_);

  // --- WhT = W^T x^T  (per head), bf16 out [H][128][n] ---
  gemm_kernel<<<dim3(2, N_ / 128, H_), dim3(256), 0, stream>>>(
      WgT, xb, D_, D_, D_, D_, nullptr, WhTg, nullptr, N_, 0,
      (long)D_ * D_, 0, (long)D_ * N_);
  gemm_kernel<<<dim3(2, T_ / 128, H_), dim3(256), 0, stream>>>(
      WtT, txb, D_, D_, D_, D_, nullptr, WhTt, nullptr, T_, 0,
      (long)D_ * D_, 0, (long)D_ * T_);

  // --- attention (barrier-free, direct hcat output) ---
  attn_kernel<<<dim3(N_ / 32, H_), dim3(256), 0, stream>>>(
      WhTg, (const unsigned char*)bitsG, fsAg, fdAg, hcatG, N_);
  attn_kernel<<<dim3(T_ / 32, H_), dim3(256), 0, stream>>>(
      WhTt, (const unsigned char*)bitsT, fsAt, fdAt, hcatT, T_);

  // --- head-concat FC: concept (fp32) and gat_text (bf16, transposed) ---
  gemm_kernel<<<dim3(N_ / 64, 1, 1), dim3(256), 0, stream>>>(
      hcatG, fcgT, N_, HD_, HD_, HD_, conceptF, nullptr, fcg_b, D_, 1, 0, 0, 0);
  gemm_kernel<<<dim3(T_ / 64, 1, 1), dim3(256), 0, stream>>>(
      hcatT, fctT, T_, HD_, HD_, HD_, nullptr, gatT, fct_b, T_, 2, 0, 0, 0);

  // --- c_text partials = tfidf^T @ gat_text (k-split Sc) ---
  gemm_kernel<<<dim3(N_ / 64, 1, Sc), dim3(256), 0, stream>>>(
      tfidfT, gatT, N_, T_ / Sc, T_, T_, ctextP, nullptr, nullptr, D_, 3,
      (long)(T_ / Sc), (long)(T_ / Sc), (long)N_ * D_);

  // --- gated fusion + final linear + relu ---
  fusion_kernel<<<dim3(N_ / 64), dim3(256), 0, stream>>>(conceptF, ctextP, Sc, (long)N_ * D_,
                                                         fusT, fus_b, out);
}

// Round 5
// 470.666 us; speedup vs baseline: 1.5440x; 1.5440x over previous
//
#include <hip/hip_runtime.h>
#include <hip/hip_bf16.h>
#include <stdint.h>

#define N_  6144
#define T_  3072
#define D_  128
#define H_  4
#define HD_ 512

typedef float f32x4 __attribute__((ext_vector_type(4)));
typedef short s16x8 __attribute__((ext_vector_type(8)));

#define GLL16(g, s) __builtin_amdgcn_global_load_lds( \
    (const __attribute__((address_space(1))) unsigned int*)(g), \
    (__attribute__((address_space(3))) unsigned int*)(s), 16, 0, 0)

static __device__ __forceinline__ short f2bf(float f) {
  union { __hip_bfloat16 b; short s; } u;
  u.b = __float2bfloat16(f);
  return u.s;
}

// ---------------- adj (int32 0/1) -> bitmask ----------------
__global__ __launch_bounds__(256) void bits_kernel(const int* __restrict__ adj,
                                                   unsigned long long* __restrict__ bits,
                                                   int nwords) {
  int lane = threadIdx.x & 63;
  int gw = (blockIdx.x * blockDim.x + threadIdx.x) >> 6;
  int nw = (gridDim.x * blockDim.x) >> 6;
  for (int w = gw; w < nwords; w += nw) {
    int v = adj[(long)w * 64 + lane];
    unsigned long long b = __ballot(v != 0);
    if (lane == 0) bits[w] = b;
  }
}

// ---------------- fp32 -> bf16 (same layout) ----------------
__global__ __launch_bounds__(256) void cvt_kernel(const float* __restrict__ in,
                                                  short* __restrict__ out, int count4) {
  int i = blockIdx.x * blockDim.x + threadIdx.x;
  if (i < count4) {
    float4 v = *(const float4*)(in + (long)i * 4);
    short4 o;
    o.x = f2bf(v.x); o.y = f2bf(v.y); o.z = f2bf(v.z); o.w = f2bf(v.w);
    *(short4*)(out + (long)i * 4) = o;
  }
}

// ---------------- fp32 [R][C] -> bf16 [C][R] (batched) ----------------
__global__ __launch_bounds__(256) void tcvt_kernel(const float* __restrict__ in,
                                                   short* __restrict__ out,
                                                   int R, int C, long sIn, long sOut) {
  __shared__ float t[32][33];
  in += (long)blockIdx.z * sIn;
  out += (long)blockIdx.z * sOut;
  int c0 = blockIdx.x * 32, r0 = blockIdx.y * 32;
  int tx = threadIdx.x, ty = threadIdx.y;   // block (32,8)
#pragma unroll
  for (int i = 0; i < 4; ++i)
    t[ty + 8 * i][tx] = in[(long)(r0 + ty + 8 * i) * C + c0 + tx];
  __syncthreads();
#pragma unroll
  for (int i = 0; i < 4; ++i)
    out[(long)(c0 + ty + 8 * i) * R + r0 + tx] = f2bf(t[tx][ty + 8 * i]);
}

// ---------------- u_s[h][d] = sum_e W[h][d][e]*a_src[h][e] ----------------
__global__ void headvec_kernel(const float* __restrict__ W, const float* __restrict__ a_s,
                               const float* __restrict__ a_d, float* __restrict__ u_s,
                               float* __restrict__ u_d) {
  int h = blockIdx.x, d = threadIdx.x;
  const float* wr = W + ((long)h * D_ + d) * D_;
  const float* as = a_s + h * D_;
  const float* ad = a_d + h * D_;
  float s = 0.f, t = 0.f;
#pragma unroll 8
  for (int e = 0; e < D_; ++e) { s += wr[e] * as[e]; t += wr[e] * ad[e]; }
  u_s[h * D_ + d] = s;
  u_d[h * D_ + d] = t;
}

// ---------------- f_s/f_d (pre-scaled by log2e) ----------------
__global__ __launch_bounds__(256) void fvec_kernel(const float* __restrict__ x,
                                                   const float* __restrict__ u_s,
                                                   const float* __restrict__ u_d,
                                                   float* __restrict__ fsA,
                                                   float* __restrict__ fdA,
                                                   int n) {
  __shared__ float usl[128], udl[128];
  long idx = (long)blockIdx.x * 256 + threadIdx.x;
  int h = (int)(idx / n), i = (int)(idx % n);
  if (threadIdx.x < 128) {
    usl[threadIdx.x] = u_s[h * D_ + threadIdx.x];
    udl[threadIdx.x] = u_d[h * D_ + threadIdx.x];
  }
  __syncthreads();
  const float4* xr = (const float4*)(x + (long)i * D_);
  float s = 0.f, t = 0.f;
#pragma unroll 8
  for (int e4 = 0; e4 < 32; ++e4) {
    float4 xv = xr[e4];
    s += xv.x * usl[4 * e4] + xv.y * usl[4 * e4 + 1] + xv.z * usl[4 * e4 + 2] + xv.w * usl[4 * e4 + 3];
    t += xv.x * udl[4 * e4] + xv.y * udl[4 * e4 + 1] + xv.z * udl[4 * e4 + 2] + xv.w * udl[4 * e4 + 3];
  }
  const float L2E = 1.4426950408889634f;
  fsA[idx] = s * L2E;
  fdA[idx] = t * L2E;
}

// ---------------- generic bf16 MFMA GEMM (global_load_lds staging, 1 barrier/iter) ----
// tile 64 rows x 128 cols, K in steps of 32.
// epi: 0 = bf16 store, 3 = fp32 plain partial (+bz*sOut)
__global__ __launch_bounds__(256) void gemm_kernel(const short* __restrict__ A,
                                                   const short* __restrict__ BT,
                                                   int K, int lda, int ldb,
                                                   float* __restrict__ outF, short* __restrict__ outB,
                                                   int ldo, int epi,
                                                   long sA, long sBT, long sOut) {
  int bz = blockIdx.z;
  A += bz * sA;
  BT += bz * sBT;
  __shared__ __align__(16) short bs[2][4096];
  int tid = threadIdx.x, w = tid >> 6, l = tid & 63, lm = l & 15, lg = l >> 4;
  int row0 = blockIdx.x * 64 + w * 16;
  int col0 = blockIdx.y * 128;
  const short* arow = A + (long)(row0 + lm) * lda + 8 * lg;
  const short* bsrc = BT + (long)(col0 + 16 * (2 * w) + lm) * ldb + 8 * lg;
  f32x4 acc[8] = {};
  int nt = K / 32;
  s16x8 af = *(const s16x8*)(arow);
  for (int kt = 0; kt < nt; ++kt) {
    int sl = kt & 1, kb = kt * 32;
    GLL16(bsrc + kb, &bs[sl][(2 * w) * 512]);
    GLL16(bsrc + kb + 16 * ldb, &bs[sl][(2 * w + 1) * 512]);
    s16x8 an = (kt + 1 < nt) ? *(const s16x8*)(arow + kb + 32) : af;
    __syncthreads();
#pragma unroll
    for (int f = 0; f < 8; ++f) {
      s16x8 bf = *(const s16x8*)(&bs[sl][f * 512 + l * 8]);
      acc[f] = __builtin_amdgcn_mfma_f32_16x16x32_bf16(af, bf, acc[f], 0, 0, 0);
    }
    af = an;
  }
#pragma unroll
  for (int f = 0; f < 8; ++f) {
    int col = col0 + 16 * f + lm;
#pragma unroll
    for (int r = 0; r < 4; ++r) {
      int row = row0 + 4 * lg + r;
      if (epi == 0) outB[bz * sOut + (long)row * ldo + col] = f2bf(acc[f][r]);
      else          outF[bz * sOut + (long)row * ldo + col] = acc[f][r];
    }
  }
}

// ---------------- reduce k-split fc partials: sum + bias + relu ----------------
// mode 0: fp32 row-major out. mode 1: bf16 transposed out (out[d][row]).
__global__ __launch_bounds__(256) void reduce_kernel(const float* __restrict__ P,
                                                     int S, long sP,
                                                     const float* __restrict__ bias,
                                                     float* __restrict__ outF,
                                                     short* __restrict__ outB,
                                                     int ldo, int mode) {
  __shared__ short sm[128][68];
  int tid = threadIdx.x;
  int r0 = blockIdx.x * 64;
#pragma unroll
  for (int k = 0; k < 8; ++k) {
    int e = tid * 4 + k * 1024;
    int row = e >> 7, col = e & 127;
    f32x4 v = {};
    for (int s = 0; s < S; ++s)
      v += *(const f32x4*)(P + (long)s * sP + (long)(r0 + row) * 128 + col);
    const float4 bv = *(const float4*)(bias + col);
    v[0] += bv.x; v[1] += bv.y; v[2] += bv.z; v[3] += bv.w;
#pragma unroll
    for (int q = 0; q < 4; ++q) v[q] = v[q] > 0.f ? v[q] : 0.f;
    if (mode == 0) {
      *(f32x4*)(outF + (long)(r0 + row) * 128 + col) = v;
    } else {
      sm[col + 0][row] = f2bf(v[0]);
      sm[col + 1][row] = f2bf(v[1]);
      sm[col + 2][row] = f2bf(v[2]);
      sm[col + 3][row] = f2bf(v[3]);
    }
  }
  if (mode == 1) {
    __syncthreads();
    int d = tid >> 1, seg = tid & 1;
    short* dst = outB + (long)d * ldo + r0 + seg * 32;
#pragma unroll
    for (int q = 0; q < 8; ++q) {
      short4 o;
      o.x = sm[d][seg * 32 + 4 * q + 0];
      o.y = sm[d][seg * 32 + 4 * q + 1];
      o.z = sm[d][seg * 32 + 4 * q + 2];
      o.w = sm[d][seg * 32 + 4 * q + 3];
      *(short4*)(dst + 4 * q) = o;
    }
  }
}

// ---------------- fused masked-softmax attention ----------------
// grid (n/64, H, S), block 256 (4 waves; wave w owns rows 16w..16w+15).
// global_load_lds staging of the shared B tile, 1 barrier/iter, P-gen fills drain.
__global__ __launch_bounds__(256) void attn_kernel(const short* __restrict__ WhT,
                                                   const unsigned char* __restrict__ bits,
                                                   const float* __restrict__ fsA,
                                                   const float* __restrict__ fdA,
                                                   float* __restrict__ pacc,
                                                   float* __restrict__ pz,
                                                   int n, int S) {
  int h = blockIdx.y, sp = blockIdx.z;
  int RB = gridDim.x;
  int klen = n / S, k0 = sp * klen;
  const short* whT = WhT + (long)h * D_ * n;
  const float* fa = fdA + (long)h * n;
  __shared__ __align__(16) short bs[2][4096];
  int tid = threadIdx.x, w = tid >> 6, l = tid & 63, lm = l & 15, lg = l >> 4;
  int i0 = blockIdx.x * 64;
  int irow = i0 + 16 * w + lm;
  float fs = fsA[(long)h * n + irow];
  const unsigned char* brow = bits + (long)irow * (n >> 3);
  const short* bsrc = whT + (long)(16 * (2 * w) + lm) * n + 8 * lg + k0;
  f32x4 acc[8] = {};
  float z = 0.f;
  int nt = klen / 32;
  float favC[8];
  unsigned mbC;
  *(float4*)(favC)     = *(const float4*)(fa + k0 + 8 * lg);
  *(float4*)(favC + 4) = *(const float4*)(fa + k0 + 8 * lg + 4);
  mbC = (*(const unsigned*)(brow + (k0 >> 3))) >> (8 * lg);
  for (int kt = 0; kt < nt; ++kt) {
    int sl = kt & 1, kb = kt * 32;
    GLL16(bsrc + kb, &bs[sl][(2 * w) * 512]);
    GLL16(bsrc + kb + 16 * n, &bs[sl][(2 * w + 1) * 512]);
    int kn = k0 + (kt + 1 < nt ? kb + 32 : kb);
    float favN[8];
    unsigned mbN;
    *(float4*)(favN)     = *(const float4*)(fa + kn + 8 * lg);
    *(float4*)(favN + 4) = *(const float4*)(fa + kn + 8 * lg + 4);
    mbN = (*(const unsigned*)(brow + (kn >> 3))) >> (8 * lg);
    // P-gen (register-only) fills the barrier-drain shadow
    union { s16x8 v; unsigned u[4]; } af;
#pragma unroll
    for (int jj = 0; jj < 4; ++jj) {
      float ua = fs + favC[2 * jj], ub = fs + favC[2 * jj + 1];
      ua = ((mbC >> (2 * jj)) & 1u) ? ua : -1e30f;
      ub = ((mbC >> (2 * jj + 1)) & 1u) ? ub : -1e30f;
      float pa = __builtin_amdgcn_exp2f(fmaxf(ua, 0.2f * ua));
      float pb = __builtin_amdgcn_exp2f(fmaxf(ub, 0.2f * ub));
      z += pa + pb;
      af.u[jj] = __builtin_amdgcn_perm(__float_as_uint(pb) + 0x8000u,
                                       __float_as_uint(pa) + 0x8000u, 0x07060302);
    }
    __syncthreads();
#pragma unroll
    for (int f = 0; f < 8; ++f) {
      s16x8 bf = *(const s16x8*)(&bs[sl][f * 512 + l * 8]);
      acc[f] = __builtin_amdgcn_mfma_f32_16x16x32_bf16(af.v, bf, acc[f], 0, 0, 0);
    }
#pragma unroll
    for (int j = 0; j < 8; ++j) favC[j] = favN[j];
    mbC = mbN;
  }
  z += __shfl_xor(z, 16);
  z += __shfl_xor(z, 32);
  long base = (long)(h * RB + blockIdx.x) * S + sp;
  if (l < 16) pz[base * 64 + 16 * w + lm] = z;
  long pb = base * 8192;
#pragma unroll
  for (int f = 0; f < 8; ++f)
#pragma unroll
    for (int r = 0; r < 4; ++r)
      pacc[pb + (long)(16 * w + 4 * lg + r) * 128 + 16 * f + lm] = acc[f][r];
}

// ---------------- combine k-split partials: /Z, elu, write bf16 head-concat ----------------
__global__ __launch_bounds__(256) void attn_combine_kernel(const float* __restrict__ pacc,
                                                           const float* __restrict__ pz,
                                                           short* __restrict__ hcat,
                                                           int S) {
  int h = blockIdx.y, rb = blockIdx.x;
  int RB = gridDim.x;
  long base = (long)(h * RB + rb) * S;
  __shared__ float zl[64];
  int tid = threadIdx.x;
  if (tid < 64) {
    float zv = 0.f;
    for (int s = 0; s < S; ++s) zv += pz[(base + s) * 64 + tid];
    zl[tid] = 1.f / zv;
  }
  __syncthreads();
  int i0 = rb * 64;
#pragma unroll
  for (int k = 0; k < 8; ++k) {
    int e = tid * 4 + k * 1024;
    int row = e >> 7, col = e & 127;
    f32x4 v = {};
    for (int s = 0; s < S; ++s) v += *(const f32x4*)(pacc + (base + s) * 8192 + e);
    float iz = zl[row];
    short4 o;
    float t;
    t = v[0] * iz; o.x = f2bf(t > 0.f ? t : __expf(t) - 1.f);
    t = v[1] * iz; o.y = f2bf(t > 0.f ? t : __expf(t) - 1.f);
    t = v[2] * iz; o.z = f2bf(t > 0.f ? t : __expf(t) - 1.f);
    t = v[3] * iz; o.w = f2bf(t > 0.f ? t : __expf(t) - 1.f);
    *(short4*)(hcat + (long)(i0 + row) * HD_ + h * D_ + col) = o;
  }
}

// ---------------- gated fusion (ctext from Sc partials) + final GEMM + relu ----------------
__global__ __launch_bounds__(256) void fusion_kernel(const float* __restrict__ concept,
                                                     const float* __restrict__ ctextP,
                                                     int Sc, long sCt,
                                                     const short* __restrict__ fusT,
                                                     const float* __restrict__ fus_b,
                                                     float* __restrict__ out) {
  __shared__ __align__(16) short als[64 * 136];
  int tid = threadIdx.x;
  int r0 = blockIdx.x * 64;
#pragma unroll
  for (int it = 0; it < 8; ++it) {
    int e = it * 1024 + tid * 4;
    int r = e >> 7, c = e & 127;
    float4 cv = *(const float4*)(concept + (long)(r0 + r) * D_ + c);
    f32x4 tv = {};
    for (int s = 0; s < Sc; ++s)
      tv += *(const f32x4*)(ctextP + (long)s * sCt + (long)(r0 + r) * D_ + c);
    short4 o;
    {
      float s0 = cv.x + tv[0]; float z = 1.f / (1.f + __expf(-s0)); o.x = f2bf(tv[0] + z * (cv.x - tv[0]));
      s0 = cv.y + tv[1]; z = 1.f / (1.f + __expf(-s0)); o.y = f2bf(tv[1] + z * (cv.y - tv[1]));
      s0 = cv.z + tv[2]; z = 1.f / (1.f + __expf(-s0)); o.z = f2bf(tv[2] + z * (cv.z - tv[2]));
      s0 = cv.w + tv[3]; z = 1.f / (1.f + __expf(-s0)); o.w = f2bf(tv[3] + z * (cv.w - tv[3]));
    }
    *(short4*)(als + (long)r * 136 + c) = o;
  }
  __syncthreads();
  int w = tid >> 6, l = tid & 63, lm = l & 15, lg = l >> 4;
  f32x4 acc[8] = {};
#pragma unroll
  for (int kt = 0; kt < 4; ++kt) {
    int kb = kt * 32;
    s16x8 af = *(const s16x8*)(als + (16 * w + lm) * 136 + kb + 8 * lg);
#pragma unroll
    for (int f = 0; f < 8; ++f) {
      s16x8 bf = *(const s16x8*)(fusT + (long)(16 * f + lm) * D_ + kb + 8 * lg);
      acc[f] = __builtin_amdgcn_mfma_f32_16x16x32_bf16(af, bf, acc[f], 0, 0, 0);
    }
  }
#pragma unroll
  for (int f = 0; f < 8; ++f) {
    int col = 16 * f + lm;
#pragma unroll
    for (int r = 0; r < 4; ++r) {
      float v = acc[f][r] + fus_b[col];
      v = v > 0.f ? v : 0.f;
      out[(long)(r0 + 16 * w + 4 * lg + r) * D_ + col] = v;
    }
  }
}

extern "C" void kernel_launch(void* const* d_in, const int* in_sizes, int n_in,
                              void* d_out, int out_size, void* d_ws, size_t ws_size,
                              hipStream_t stream) {
  (void)in_sizes; (void)n_in; (void)out_size;
  const float* x      = (const float*)d_in[0];
  const int*   adj    = (const int*)d_in[1];
  const float* t_x    = (const float*)d_in[2];
  const int*   t_adj  = (const int*)d_in[3];
  const float* tfidf  = (const float*)d_in[4];
  const float* Wg     = (const float*)d_in[5];
  const float* ag_src = (const float*)d_in[6];
  const float* ag_dst = (const float*)d_in[7];
  const float* fcg_W  = (const float*)d_in[8];
  const float* fcg_b  = (const float*)d_in[9];
  const float* Wt     = (const float*)d_in[10];
  const float* at_src = (const float*)d_in[11];
  const float* at_dst = (const float*)d_in[12];
  const float* fct_W  = (const float*)d_in[13];
  const float* fct_b  = (const float*)d_in[14];
  const float* fus_W  = (const float*)d_in[15];
  const float* fus_b  = (const float*)d_in[16];
  float* out = (float*)d_out;

  char* ws = (char*)d_ws;
  size_t off = 0;
  auto alloc = [&](size_t bytes) -> char* {
    char* p = ws + off;
    off = (off + bytes + 255) & ~(size_t)255;
    return p;
  };
  unsigned long long* bitsG = (unsigned long long*)alloc((size_t)N_ * N_ / 8);
  unsigned long long* bitsT = (unsigned long long*)alloc((size_t)T_ * T_ / 8);
  short* xb     = (short*)alloc((size_t)N_ * D_ * 2);
  short* txb    = (short*)alloc((size_t)T_ * D_ * 2);
  short* WgT    = (short*)alloc((size_t)H_ * D_ * D_ * 2);
  short* WtT    = (short*)alloc((size_t)H_ * D_ * D_ * 2);
  short* fcgT   = (short*)alloc((size_t)HD_ * D_ * 2);
  short* fctT   = (short*)alloc((size_t)HD_ * D_ * 2);
  short* fusT   = (short*)alloc((size_t)D_ * D_ * 2);
  short* tfidfT = (short*)alloc((size_t)N_ * T_ * 2);
  short* WhTg   = (short*)alloc((size_t)H_ * D_ * N_ * 2);
  short* WhTt   = (short*)alloc((size_t)H_ * D_ * T_ * 2);
  float* usG = (float*)alloc(H_ * D_ * 4);
  float* udG = (float*)alloc(H_ * D_ * 4);
  float* usT = (float*)alloc(H_ * D_ * 4);
  float* udT = (float*)alloc(H_ * D_ * 4);
  float* fsAg = (float*)alloc((size_t)H_ * N_ * 4);
  float* fdAg = (float*)alloc((size_t)H_ * N_ * 4);
  float* fsAt = (float*)alloc((size_t)H_ * T_ * 4);
  float* fdAt = (float*)alloc((size_t)H_ * T_ * 4);
  short* hcatG = (short*)alloc((size_t)N_ * HD_ * 2);
  short* hcatT = (short*)alloc((size_t)T_ * HD_ * 2);
  short* gatT  = (short*)alloc((size_t)D_ * T_ * 2);
  float* conceptF = (float*)alloc((size_t)N_ * D_ * 4);

  // k-split scratch
  const int RBg = N_ / 64, RBt = T_ / 64;          // 96, 48
  const size_t paccG1 = (size_t)H_ * RBg * 8192 * 4;   // 12.6 MB per split
  const size_t paccT1 = (size_t)H_ * RBt * 8192 * 4;   // 6.3 MB per split
  const size_t pzG1   = (size_t)H_ * RBg * 64 * 4;
  const size_t pzT1   = (size_t)H_ * RBt * 64 * 4;
  const size_t fcPg1  = (size_t)N_ * D_ * 4;           // 3.1 MB per split
  const size_t fcPt1  = (size_t)T_ * D_ * 4;           // 1.6 MB per split
  const size_t ctp1   = (size_t)N_ * D_ * 4;           // 3.1 MB per split
  size_t rem = (ws_size > off + (1 << 20)) ? (ws_size - off - (1 << 20)) : 0;
  int Sg = 1, St = 1, Sf = 1, Sc = 1;
  size_t needFull = 4 * (paccG1 + pzG1) + 4 * (paccT1 + pzT1) + 4 * fcPg1 + 4 * fcPt1 + 4 * ctp1;
  size_t needMid  = 2 * (paccG1 + pzG1) + 2 * (paccT1 + pzT1) + 2 * fcPg1 + 2 * fcPt1 + 2 * ctp1;
  if (rem >= needFull)      { Sg = 4; St = 4; Sf = 4; Sc = 4; }
  else if (rem >= needMid)  { Sg = 2; St = 2; Sf = 2; Sc = 2; }
  float* paccG = (float*)alloc(Sg * paccG1);
  float* pzG   = (float*)alloc(Sg * pzG1);
  float* paccT = (float*)alloc(St * paccT1);
  float* pzT   = (float*)alloc(St * pzT1);
  float* fcPg  = (float*)alloc(Sf * fcPg1);
  float* fcPt  = (float*)alloc(Sf * fcPt1);
  float* ctextP = (float*)alloc(Sc * ctp1);

  // --- prep ---
  bits_kernel<<<dim3(1024), dim3(256), 0, stream>>>(adj, bitsG, N_ * N_ / 64);
  bits_kernel<<<dim3(512), dim3(256), 0, stream>>>(t_adj, bitsT, T_ * T_ / 64);
  cvt_kernel<<<dim3(N_ * D_ / 1024), dim3(256), 0, stream>>>(x, xb, N_ * D_ / 4);
  cvt_kernel<<<dim3(T_ * D_ / 1024), dim3(256), 0, stream>>>(t_x, txb, T_ * D_ / 4);
  tcvt_kernel<<<dim3(4, 4, 4), dim3(32, 8), 0, stream>>>(Wg, WgT, D_, D_, (long)D_ * D_, (long)D_ * D_);
  tcvt_kernel<<<dim3(4, 4, 4), dim3(32, 8), 0, stream>>>(Wt, WtT, D_, D_, (long)D_ * D_, (long)D_ * D_);
  tcvt_kernel<<<dim3(4, 16, 1), dim3(32, 8), 0, stream>>>(fcg_W, fcgT, HD_, D_, 0, 0);
  tcvt_kernel<<<dim3(4, 16, 1), dim3(32, 8), 0, stream>>>(fct_W, fctT, HD_, D_, 0, 0);
  tcvt_kernel<<<dim3(4, 4, 1), dim3(32, 8), 0, stream>>>(fus_W, fusT, D_, D_, 0, 0);
  tcvt_kernel<<<dim3(N_ / 32, T_ / 32, 1), dim3(32, 8), 0, stream>>>(tfidf, tfidfT, T_, N_, 0, 0);
  headvec_kernel<<<dim3(H_), dim3(128), 0, stream>>>(Wg, ag_src, ag_dst, usG, udG);
  headvec_kernel<<<dim3(H_), dim3(128), 0, stream>>>(Wt, at_src, at_dst, usT, udT);
  fvec_kernel<<<dim3(H_ * N_ / 256), dim3(256), 0, stream>>>(x, usG, udG, fsAg, fdAg, N_);
  fvec_kernel<<<dim3(H_ * T_ / 256), dim3(256), 0, stream>>>(t_x, usT, udT, fsAt, fdAt, T_);

  // --- WhT = W^T x^T  (per head), bf16 out [H][128][n] ---
  gemm_kernel<<<dim3(2, N_ / 128, H_), dim3(256), 0, stream>>>(
      WgT, xb, D_, D_, D_, nullptr, WhTg, N_, 0, (long)D_ * D_, 0, (long)D_ * N_);
  gemm_kernel<<<dim3(2, T_ / 128, H_), dim3(256), 0, stream>>>(
      WtT, txb, D_, D_, D_, nullptr, WhTt, T_, 0, (long)D_ * D_, 0, (long)D_ * T_);

  // --- attention (k-split partials + combine) ---
  attn_kernel<<<dim3(RBg, H_, Sg), dim3(256), 0, stream>>>(
      WhTg, (const unsigned char*)bitsG, fsAg, fdAg, paccG, pzG, N_, Sg);
  attn_combine_kernel<<<dim3(RBg, H_), dim3(256), 0, stream>>>(paccG, pzG, hcatG, Sg);
  attn_kernel<<<dim3(RBt, H_, St), dim3(256), 0, stream>>>(
      WhTt, (const unsigned char*)bitsT, fsAt, fdAt, paccT, pzT, T_, St);
  attn_combine_kernel<<<dim3(RBt, H_), dim3(256), 0, stream>>>(paccT, pzT, hcatT, St);

  // --- head-concat FC (k-split + reduce): concept fp32, gat_text bf16 transposed ---
  gemm_kernel<<<dim3(N_ / 64, 1, Sf), dim3(256), 0, stream>>>(
      hcatG, fcgT, HD_ / Sf, HD_, HD_, fcPg, nullptr, D_, 3,
      (long)(HD_ / Sf), (long)(HD_ / Sf), (long)N_ * D_);
  reduce_kernel<<<dim3(N_ / 64), dim3(256), 0, stream>>>(
      fcPg, Sf, (long)N_ * D_, fcg_b, conceptF, nullptr, 0, 0);
  gemm_kernel<<<dim3(T_ / 64, 1, Sf), dim3(256), 0, stream>>>(
      hcatT, fctT, HD_ / Sf, HD_, HD_, fcPt, nullptr, D_, 3,
      (long)(HD_ / Sf), (long)(HD_ / Sf), (long)T_ * D_);
  reduce_kernel<<<dim3(T_ / 64), dim3(256), 0, stream>>>(
      fcPt, Sf, (long)T_ * D_, fct_b, nullptr, gatT, T_, 1);

  // --- c_text partials = tfidf^T @ gat_text (k-split Sc) ---
  gemm_kernel<<<dim3(N_ / 64, 1, Sc), dim3(256), 0, stream>>>(
      tfidfT, gatT, T_ / Sc, T_, T_, ctextP, nullptr, D_, 3,
      (long)(T_ / Sc), (long)(T_ / Sc), (long)N_ * D_);

  // --- gated fusion + final linear + relu ---
  fusion_kernel<<<dim3(N_ / 64), dim3(256), 0, stream>>>(conceptF, ctextP, Sc, (long)N_ * D_,
                                                         fusT, fus_b, out);
}

// Round 6
// 453.950 us; speedup vs baseline: 1.6009x; 1.0368x over previous
//
#include <hip/hip_runtime.h>
#include <hip/hip_bf16.h>
#include <stdint.h>

#define N_  6144
#define T_  3072
#define D_  128
#define H_  4
#define HD_ 512

typedef float f32x4 __attribute__((ext_vector_type(4)));
typedef short s16x8 __attribute__((ext_vector_type(8)));

#define GLL16(g, s) __builtin_amdgcn_global_load_lds( \
    (const __attribute__((address_space(1))) unsigned int*)(g), \
    (__attribute__((address_space(3))) unsigned int*)(s), 16, 0, 0)

static __device__ __forceinline__ short f2bf(float f) {
  union { __hip_bfloat16 b; short s; } u;
  u.b = __float2bfloat16(f);
  return u.s;
}

// ---------------- adj (int32 0/1) -> bitmask ----------------
__global__ __launch_bounds__(256) void bits_kernel(const int* __restrict__ adj,
                                                   unsigned long long* __restrict__ bits,
                                                   int nwords) {
  int lane = threadIdx.x & 63;
  int gw = (blockIdx.x * blockDim.x + threadIdx.x) >> 6;
  int nw = (gridDim.x * blockDim.x) >> 6;
  for (int w = gw; w < nwords; w += nw) {
    int v = adj[(long)w * 64 + lane];
    unsigned long long b = __ballot(v != 0);
    if (lane == 0) bits[w] = b;
  }
}

// ---------------- fp32 -> bf16 (same layout) ----------------
__global__ __launch_bounds__(256) void cvt_kernel(const float* __restrict__ in,
                                                  short* __restrict__ out, int count4) {
  int i = blockIdx.x * blockDim.x + threadIdx.x;
  if (i < count4) {
    float4 v = *(const float4*)(in + (long)i * 4);
    short4 o;
    o.x = f2bf(v.x); o.y = f2bf(v.y); o.z = f2bf(v.z); o.w = f2bf(v.w);
    *(short4*)(out + (long)i * 4) = o;
  }
}

// ---------------- fp32 [R][C] -> bf16 [C][R] (batched) ----------------
__global__ __launch_bounds__(256) void tcvt_kernel(const float* __restrict__ in,
                                                   short* __restrict__ out,
                                                   int R, int C, long sIn, long sOut) {
  __shared__ float t[32][33];
  in += (long)blockIdx.z * sIn;
  out += (long)blockIdx.z * sOut;
  int c0 = blockIdx.x * 32, r0 = blockIdx.y * 32;
  int tx = threadIdx.x, ty = threadIdx.y;   // block (32,8)
#pragma unroll
  for (int i = 0; i < 4; ++i)
    t[ty + 8 * i][tx] = in[(long)(r0 + ty + 8 * i) * C + c0 + tx];
  __syncthreads();
#pragma unroll
  for (int i = 0; i < 4; ++i)
    out[(long)(c0 + ty + 8 * i) * R + r0 + tx] = f2bf(t[tx][ty + 8 * i]);
}

// ---------------- u_s[h][d] = sum_e W[h][d][e]*a_src[h][e] ----------------
__global__ void headvec_kernel(const float* __restrict__ W, const float* __restrict__ a_s,
                               const float* __restrict__ a_d, float* __restrict__ u_s,
                               float* __restrict__ u_d) {
  int h = blockIdx.x, d = threadIdx.x;
  const float* wr = W + ((long)h * D_ + d) * D_;
  const float* as = a_s + h * D_;
  const float* ad = a_d + h * D_;
  float s = 0.f, t = 0.f;
#pragma unroll 8
  for (int e = 0; e < D_; ++e) { s += wr[e] * as[e]; t += wr[e] * ad[e]; }
  u_s[h * D_ + d] = s;
  u_d[h * D_ + d] = t;
}

// ---------------- f_s/f_d (pre-scaled by log2e) ----------------
__global__ __launch_bounds__(256) void fvec_kernel(const float* __restrict__ x,
                                                   const float* __restrict__ u_s,
                                                   const float* __restrict__ u_d,
                                                   float* __restrict__ fsA,
                                                   float* __restrict__ fdA,
                                                   int n) {
  __shared__ float usl[128], udl[128];
  long idx = (long)blockIdx.x * 256 + threadIdx.x;
  int h = (int)(idx / n), i = (int)(idx % n);
  if (threadIdx.x < 128) {
    usl[threadIdx.x] = u_s[h * D_ + threadIdx.x];
    udl[threadIdx.x] = u_d[h * D_ + threadIdx.x];
  }
  __syncthreads();
  const float4* xr = (const float4*)(x + (long)i * D_);
  float s = 0.f, t = 0.f;
#pragma unroll 8
  for (int e4 = 0; e4 < 32; ++e4) {
    float4 xv = xr[e4];
    s += xv.x * usl[4 * e4] + xv.y * usl[4 * e4 + 1] + xv.z * usl[4 * e4 + 2] + xv.w * usl[4 * e4 + 3];
    t += xv.x * udl[4 * e4] + xv.y * udl[4 * e4 + 1] + xv.z * udl[4 * e4 + 2] + xv.w * udl[4 * e4 + 3];
  }
  const float L2E = 1.4426950408889634f;
  fsA[idx] = s * L2E;
  fdA[idx] = t * L2E;
}

// ---------------- generic bf16 MFMA GEMM (counted-vmcnt pipeline, 3 LDS bufs) ----
// tile 64 rows x 128 cols, K in steps of 32.
// epi: 0 = bf16 store, 3 = fp32 plain partial (+bz*sOut)
__global__ __launch_bounds__(256) void gemm_kernel(const short* __restrict__ A,
                                                   const short* __restrict__ BT,
                                                   int K, int lda, int ldb,
                                                   float* __restrict__ outF, short* __restrict__ outB,
                                                   int ldo, int epi,
                                                   long sA, long sBT, long sOut) {
  int bz = blockIdx.z;
  A += bz * sA;
  BT += bz * sBT;
  __shared__ __align__(16) short bs[3][4096];
  int tid = threadIdx.x, w = tid >> 6, l = tid & 63, lm = l & 15, lg = l >> 4;
  int row0 = blockIdx.x * 64 + w * 16;
  int col0 = blockIdx.y * 128;
  const short* arow = A + (long)(row0 + lm) * lda + 8 * lg;
  const short* bsrc = BT + (long)(col0 + 16 * (2 * w) + lm) * ldb + 8 * lg;
  f32x4 acc[8] = {};
  int nt = K / 32;
  // prologue: tile 0 -> buf 0
  GLL16(bsrc, &bs[0][(2 * w) * 512]);
  GLL16(bsrc + 16 * ldb, &bs[0][(2 * w + 1) * 512]);
  s16x8 af = *(const s16x8*)(arow);
  for (int kt = 0; kt < nt; ++kt) {
    int cur = kt % 3, nxt = (kt + 1) % 3;
    int kb = (kt + 1 < nt ? kt + 1 : kt) * 32;
    GLL16(bsrc + kb, &bs[nxt][(2 * w) * 512]);
    GLL16(bsrc + kb + 16 * ldb, &bs[nxt][(2 * w + 1) * 512]);
    s16x8 an = *(const s16x8*)(arow + kb);
    // drain tile-kt loads, keep tile-(kt+1)'s 3 ops in flight
    asm volatile("s_waitcnt vmcnt(3)" ::: "memory");
    __builtin_amdgcn_sched_barrier(0);
    __builtin_amdgcn_s_barrier();
    __builtin_amdgcn_sched_barrier(0);
#pragma unroll
    for (int f = 0; f < 8; ++f) {
      s16x8 bf = *(const s16x8*)(&bs[cur][f * 512 + l * 8]);
      acc[f] = __builtin_amdgcn_mfma_f32_16x16x32_bf16(af, bf, acc[f], 0, 0, 0);
    }
    af = an;
  }
#pragma unroll
  for (int f = 0; f < 8; ++f) {
    int col = col0 + 16 * f + lm;
#pragma unroll
    for (int r = 0; r < 4; ++r) {
      int row = row0 + 4 * lg + r;
      if (epi == 0) outB[bz * sOut + (long)row * ldo + col] = f2bf(acc[f][r]);
      else          outF[bz * sOut + (long)row * ldo + col] = acc[f][r];
    }
  }
}

// ---------------- reduce k-split fc partials: sum + bias + relu ----------------
// mode 0: fp32 row-major out. mode 1: bf16 transposed out (out[d][row]).
__global__ __launch_bounds__(256) void reduce_kernel(const float* __restrict__ P,
                                                     int S, long sP,
                                                     const float* __restrict__ bias,
                                                     float* __restrict__ outF,
                                                     short* __restrict__ outB,
                                                     int ldo, int mode) {
  __shared__ short sm[128][68];
  int tid = threadIdx.x;
  int r0 = blockIdx.x * 64;
#pragma unroll
  for (int k = 0; k < 8; ++k) {
    int e = tid * 4 + k * 1024;
    int row = e >> 7, col = e & 127;
    f32x4 v = {};
    for (int s = 0; s < S; ++s)
      v += *(const f32x4*)(P + (long)s * sP + (long)(r0 + row) * 128 + col);
    const float4 bv = *(const float4*)(bias + col);
    v[0] += bv.x; v[1] += bv.y; v[2] += bv.z; v[3] += bv.w;
#pragma unroll
    for (int q = 0; q < 4; ++q) v[q] = v[q] > 0.f ? v[q] : 0.f;
    if (mode == 0) {
      *(f32x4*)(outF + (long)(r0 + row) * 128 + col) = v;
    } else {
      sm[col + 0][row] = f2bf(v[0]);
      sm[col + 1][row] = f2bf(v[1]);
      sm[col + 2][row] = f2bf(v[2]);
      sm[col + 3][row] = f2bf(v[3]);
    }
  }
  if (mode == 1) {
    __syncthreads();
    int d = tid >> 1, seg = tid & 1;
    short* dst = outB + (long)d * ldo + r0 + seg * 32;
#pragma unroll
    for (int q = 0; q < 8; ++q) {
      short4 o;
      o.x = sm[d][seg * 32 + 4 * q + 0];
      o.y = sm[d][seg * 32 + 4 * q + 1];
      o.z = sm[d][seg * 32 + 4 * q + 2];
      o.w = sm[d][seg * 32 + 4 * q + 3];
      *(short4*)(dst + 4 * q) = o;
    }
  }
}

// ---------------- fused masked-softmax attention (counted-vmcnt pipeline) ----
// grid (n/64, H, S), block 256 (4 waves; wave w owns rows 16w..16w+15).
__global__ __launch_bounds__(256) void attn_kernel(const short* __restrict__ WhT,
                                                   const unsigned char* __restrict__ bits,
                                                   const float* __restrict__ fsA,
                                                   const float* __restrict__ fdA,
                                                   float* __restrict__ pacc,
                                                   float* __restrict__ pz,
                                                   int n, int S) {
  int h = blockIdx.y, sp = blockIdx.z;
  int RB = gridDim.x;
  int klen = n / S, k0 = sp * klen;
  const short* whT = WhT + (long)h * D_ * n;
  const float* fa = fdA + (long)h * n;
  __shared__ __align__(16) short bs[3][4096];
  int tid = threadIdx.x, w = tid >> 6, l = tid & 63, lm = l & 15, lg = l >> 4;
  int i0 = blockIdx.x * 64;
  int irow = i0 + 16 * w + lm;
  float fs = fsA[(long)h * n + irow];
  const unsigned char* brow = bits + (long)irow * (n >> 3);
  const short* bsrc = whT + (long)(16 * (2 * w) + lm) * n + 8 * lg + k0;
  f32x4 acc[8] = {};
  float z = 0.f;
  int nt = klen / 32;
  // prologue: tile 0 -> buf 0, f/mask regs for tile 0
  GLL16(bsrc, &bs[0][(2 * w) * 512]);
  GLL16(bsrc + 16 * n, &bs[0][(2 * w + 1) * 512]);
  float favC[8];
  unsigned mbC;
  *(float4*)(favC)     = *(const float4*)(fa + k0 + 8 * lg);
  *(float4*)(favC + 4) = *(const float4*)(fa + k0 + 8 * lg + 4);
  mbC = (*(const unsigned*)(brow + (k0 >> 3))) >> (8 * lg);
  for (int kt = 0; kt < nt; ++kt) {
    int cur = kt % 3, nxt = (kt + 1) % 3;
    int kb = (kt + 1 < nt ? kt + 1 : kt) * 32;
    // issue next tile's staging + next f/mask loads (5 VMEM ops)
    GLL16(bsrc + kb, &bs[nxt][(2 * w) * 512]);
    GLL16(bsrc + kb + 16 * n, &bs[nxt][(2 * w + 1) * 512]);
    int kn = k0 + kb;
    float favN[8];
    unsigned mbN;
    *(float4*)(favN)     = *(const float4*)(fa + kn + 8 * lg);
    *(float4*)(favN + 4) = *(const float4*)(fa + kn + 8 * lg + 4);
    mbN = (*(const unsigned*)(brow + (kn >> 3))) >> (8 * lg);
    // P-gen for tile kt (register-only) while loads fly
    union { s16x8 v; unsigned u[4]; } af;
#pragma unroll
    for (int jj = 0; jj < 4; ++jj) {
      float ua = fs + favC[2 * jj], ub = fs + favC[2 * jj + 1];
      ua = ((mbC >> (2 * jj)) & 1u) ? ua : -1e30f;
      ub = ((mbC >> (2 * jj + 1)) & 1u) ? ub : -1e30f;
      float pa = __builtin_amdgcn_exp2f(fmaxf(ua, 0.2f * ua));
      float pb = __builtin_amdgcn_exp2f(fmaxf(ub, 0.2f * ub));
      z += pa + pb;
      af.u[jj] = __builtin_amdgcn_perm(__float_as_uint(pb) + 0x8000u,
                                       __float_as_uint(pa) + 0x8000u, 0x07060302);
    }
    // drain tile-kt staging; keep this iteration's 5 VMEM ops in flight
    asm volatile("s_waitcnt vmcnt(5)" ::: "memory");
    __builtin_amdgcn_sched_barrier(0);
    __builtin_amdgcn_s_barrier();
    __builtin_amdgcn_sched_barrier(0);
#pragma unroll
    for (int f = 0; f < 8; ++f) {
      s16x8 bf = *(const s16x8*)(&bs[cur][f * 512 + l * 8]);
      acc[f] = __builtin_amdgcn_mfma_f32_16x16x32_bf16(af.v, bf, acc[f], 0, 0, 0);
    }
#pragma unroll
    for (int j = 0; j < 8; ++j) favC[j] = favN[j];
    mbC = mbN;
  }
  z += __shfl_xor(z, 16);
  z += __shfl_xor(z, 32);
  long base = (long)(h * RB + blockIdx.x) * S + sp;
  if (l < 16) pz[base * 64 + 16 * w + lm] = z;
  long pb = base * 8192;
#pragma unroll
  for (int f = 0; f < 8; ++f)
#pragma unroll
    for (int r = 0; r < 4; ++r)
      pacc[pb + (long)(16 * w + 4 * lg + r) * 128 + 16 * f + lm] = acc[f][r];
}

// ---------------- combine k-split partials: /Z, elu, write bf16 head-concat ----------------
__global__ __launch_bounds__(256) void attn_combine_kernel(const float* __restrict__ pacc,
                                                           const float* __restrict__ pz,
                                                           short* __restrict__ hcat,
                                                           int S) {
  int h = blockIdx.y, rb = blockIdx.x;
  int RB = gridDim.x;
  long base = (long)(h * RB + rb) * S;
  __shared__ float zl[64];
  int tid = threadIdx.x;
  if (tid < 64) {
    float zv = 0.f;
    for (int s = 0; s < S; ++s) zv += pz[(base + s) * 64 + tid];
    zl[tid] = 1.f / zv;
  }
  __syncthreads();
  int i0 = rb * 64;
#pragma unroll
  for (int k = 0; k < 8; ++k) {
    int e = tid * 4 + k * 1024;
    int row = e >> 7, col = e & 127;
    f32x4 v = {};
    for (int s = 0; s < S; ++s) v += *(const f32x4*)(pacc + (base + s) * 8192 + e);
    float iz = zl[row];
    short4 o;
    float t;
    t = v[0] * iz; o.x = f2bf(t > 0.f ? t : __expf(t) - 1.f);
    t = v[1] * iz; o.y = f2bf(t > 0.f ? t : __expf(t) - 1.f);
    t = v[2] * iz; o.z = f2bf(t > 0.f ? t : __expf(t) - 1.f);
    t = v[3] * iz; o.w = f2bf(t > 0.f ? t : __expf(t) - 1.f);
    *(short4*)(hcat + (long)(i0 + row) * HD_ + h * D_ + col) = o;
  }
}

// ---------------- gated fusion (ctext from Sc partials) + final GEMM + relu ----------------
__global__ __launch_bounds__(256) void fusion_kernel(const float* __restrict__ concept,
                                                     const float* __restrict__ ctextP,
                                                     int Sc, long sCt,
                                                     const short* __restrict__ fusT,
                                                     const float* __restrict__ fus_b,
                                                     float* __restrict__ out) {
  __shared__ __align__(16) short als[64 * 136];
  int tid = threadIdx.x;
  int r0 = blockIdx.x * 64;
#pragma unroll
  for (int it = 0; it < 8; ++it) {
    int e = it * 1024 + tid * 4;
    int r = e >> 7, c = e & 127;
    float4 cv = *(const float4*)(concept + (long)(r0 + r) * D_ + c);
    f32x4 tv = {};
    for (int s = 0; s < Sc; ++s)
      tv += *(const f32x4*)(ctextP + (long)s * sCt + (long)(r0 + r) * D_ + c);
    short4 o;
    {
      float s0 = cv.x + tv[0]; float z = 1.f / (1.f + __expf(-s0)); o.x = f2bf(tv[0] + z * (cv.x - tv[0]));
      s0 = cv.y + tv[1]; z = 1.f / (1.f + __expf(-s0)); o.y = f2bf(tv[1] + z * (cv.y - tv[1]));
      s0 = cv.z + tv[2]; z = 1.f / (1.f + __expf(-s0)); o.z = f2bf(tv[2] + z * (cv.z - tv[2]));
      s0 = cv.w + tv[3]; z = 1.f / (1.f + __expf(-s0)); o.w = f2bf(tv[3] + z * (cv.w - tv[3]));
    }
    *(short4*)(als + (long)r * 136 + c) = o;
  }
  __syncthreads();
  int w = tid >> 6, l = tid & 63, lm = l & 15, lg = l >> 4;
  f32x4 acc[8] = {};
#pragma unroll
  for (int kt = 0; kt < 4; ++kt) {
    int kb = kt * 32;
    s16x8 af = *(const s16x8*)(als + (16 * w + lm) * 136 + kb + 8 * lg);
#pragma unroll
    for (int f = 0; f < 8; ++f) {
      s16x8 bf = *(const s16x8*)(fusT + (long)(16 * f + lm) * D_ + kb + 8 * lg);
      acc[f] = __builtin_amdgcn_mfma_f32_16x16x32_bf16(af, bf, acc[f], 0, 0, 0);
    }
  }
#pragma unroll
  for (int f = 0; f < 8; ++f) {
    int col = 16 * f + lm;
#pragma unroll
    for (int r = 0; r < 4; ++r) {
      float v = acc[f][r] + fus_b[col];
      v = v > 0.f ? v : 0.f;
      out[(long)(r0 + 16 * w + 4 * lg + r) * D_ + col] = v;
    }
  }
}

extern "C" void kernel_launch(void* const* d_in, const int* in_sizes, int n_in,
                              void* d_out, int out_size, void* d_ws, size_t ws_size,
                              hipStream_t stream) {
  (void)in_sizes; (void)n_in; (void)out_size;
  const float* x      = (const float*)d_in[0];
  const int*   adj    = (const int*)d_in[1];
  const float* t_x    = (const float*)d_in[2];
  const int*   t_adj  = (const int*)d_in[3];
  const float* tfidf  = (const float*)d_in[4];
  const float* Wg     = (const float*)d_in[5];
  const float* ag_src = (const float*)d_in[6];
  const float* ag_dst = (const float*)d_in[7];
  const float* fcg_W  = (const float*)d_in[8];
  const float* fcg_b  = (const float*)d_in[9];
  const float* Wt     = (const float*)d_in[10];
  const float* at_src = (const float*)d_in[11];
  const float* at_dst = (const float*)d_in[12];
  const float* fct_W  = (const float*)d_in[13];
  const float* fct_b  = (const float*)d_in[14];
  const float* fus_W  = (const float*)d_in[15];
  const float* fus_b  = (const float*)d_in[16];
  float* out = (float*)d_out;

  char* ws = (char*)d_ws;
  size_t off = 0;
  auto alloc = [&](size_t bytes) -> char* {
    char* p = ws + off;
    off = (off + bytes + 255) & ~(size_t)255;
    return p;
  };
  unsigned long long* bitsG = (unsigned long long*)alloc((size_t)N_ * N_ / 8);
  unsigned long long* bitsT = (unsigned long long*)alloc((size_t)T_ * T_ / 8);
  short* xb     = (short*)alloc((size_t)N_ * D_ * 2);
  short* txb    = (short*)alloc((size_t)T_ * D_ * 2);
  short* WgT    = (short*)alloc((size_t)H_ * D_ * D_ * 2);
  short* WtT    = (short*)alloc((size_t)H_ * D_ * D_ * 2);
  short* fcgT   = (short*)alloc((size_t)HD_ * D_ * 2);
  short* fctT   = (short*)alloc((size_t)HD_ * D_ * 2);
  short* fusT   = (short*)alloc((size_t)D_ * D_ * 2);
  short* tfidfT = (short*)alloc((size_t)N_ * T_ * 2);
  short* WhTg   = (short*)alloc((size_t)H_ * D_ * N_ * 2);
  short* WhTt   = (short*)alloc((size_t)H_ * D_ * T_ * 2);
  float* usG = (float*)alloc(H_ * D_ * 4);
  float* udG = (float*)alloc(H_ * D_ * 4);
  float* usT = (float*)alloc(H_ * D_ * 4);
  float* udT = (float*)alloc(H_ * D_ * 4);
  float* fsAg = (float*)alloc((size_t)H_ * N_ * 4);
  float* fdAg = (float*)alloc((size_t)H_ * N_ * 4);
  float* fsAt = (float*)alloc((size_t)H_ * T_ * 4);
  float* fdAt = (float*)alloc((size_t)H_ * T_ * 4);
  short* hcatG = (short*)alloc((size_t)N_ * HD_ * 2);
  short* hcatT = (short*)alloc((size_t)T_ * HD_ * 2);
  short* gatT  = (short*)alloc((size_t)D_ * T_ * 2);
  float* conceptF = (float*)alloc((size_t)N_ * D_ * 4);

  // k-split scratch
  const int RBg = N_ / 64, RBt = T_ / 64;          // 96, 48
  const size_t paccG1 = (size_t)H_ * RBg * 8192 * 4;   // 12.6 MB per split
  const size_t paccT1 = (size_t)H_ * RBt * 8192 * 4;   // 6.3 MB per split
  const size_t pzG1   = (size_t)H_ * RBg * 64 * 4;
  const size_t pzT1   = (size_t)H_ * RBt * 64 * 4;
  const size_t fcPg1  = (size_t)N_ * D_ * 4;           // 3.1 MB per split
  const size_t fcPt1  = (size_t)T_ * D_ * 4;           // 1.6 MB per split
  const size_t ctp1   = (size_t)N_ * D_ * 4;           // 3.1 MB per split
  size_t rem = (ws_size > off + (1 << 20)) ? (ws_size - off - (1 << 20)) : 0;
  int Sg = 1, St = 1, Sf = 1, Sc = 1;
  size_t needFull = 4 * (paccG1 + pzG1) + 4 * (paccT1 + pzT1) + 4 * fcPg1 + 4 * fcPt1 + 4 * ctp1;
  size_t needMid  = 2 * (paccG1 + pzG1) + 2 * (paccT1 + pzT1) + 2 * fcPg1 + 2 * fcPt1 + 2 * ctp1;
  if (rem >= needFull)      { Sg = 4; St = 4; Sf = 4; Sc = 4; }
  else if (rem >= needMid)  { Sg = 2; St = 2; Sf = 2; Sc = 2; }
  float* paccG = (float*)alloc(Sg * paccG1);
  float* pzG   = (float*)alloc(Sg * pzG1);
  float* paccT = (float*)alloc(St * paccT1);
  float* pzT   = (float*)alloc(St * pzT1);
  float* fcPg  = (float*)alloc(Sf * fcPg1);
  float* fcPt  = (float*)alloc(Sf * fcPt1);
  float* ctextP = (float*)alloc(Sc * ctp1);

  // --- prep ---
  bits_kernel<<<dim3(1024), dim3(256), 0, stream>>>(adj, bitsG, N_ * N_ / 64);
  bits_kernel<<<dim3(512), dim3(256), 0, stream>>>(t_adj, bitsT, T_ * T_ / 64);
  cvt_kernel<<<dim3(N_ * D_ / 1024), dim3(256), 0, stream>>>(x, xb, N_ * D_ / 4);
  cvt_kernel<<<dim3(T_ * D_ / 1024), dim3(256), 0, stream>>>(t_x, txb, T_ * D_ / 4);
  tcvt_kernel<<<dim3(4, 4, 4), dim3(32, 8), 0, stream>>>(Wg, WgT, D_, D_, (long)D_ * D_, (long)D_ * D_);
  tcvt_kernel<<<dim3(4, 4, 4), dim3(32, 8), 0, stream>>>(Wt, WtT, D_, D_, (long)D_ * D_, (long)D_ * D_);
  tcvt_kernel<<<dim3(4, 16, 1), dim3(32, 8), 0, stream>>>(fcg_W, fcgT, HD_, D_, 0, 0);
  tcvt_kernel<<<dim3(4, 16, 1), dim3(32, 8), 0, stream>>>(fct_W, fctT, HD_, D_, 0, 0);
  tcvt_kernel<<<dim3(4, 4, 1), dim3(32, 8), 0, stream>>>(fus_W, fusT, D_, D_, 0, 0);
  tcvt_kernel<<<dim3(N_ / 32, T_ / 32, 1), dim3(32, 8), 0, stream>>>(tfidf, tfidfT, T_, N_, 0, 0);
  headvec_kernel<<<dim3(H_), dim3(128), 0, stream>>>(Wg, ag_src, ag_dst, usG, udG);
  headvec_kernel<<<dim3(H_), dim3(128), 0, stream>>>(Wt, at_src, at_dst, usT, udT);
  fvec_kernel<<<dim3(H_ * N_ / 256), dim3(256), 0, stream>>>(x, usG, udG, fsAg, fdAg, N_);
  fvec_kernel<<<dim3(H_ * T_ / 256), dim3(256), 0, stream>>>(t_x, usT, udT, fsAt, fdAt, T_);

  // --- WhT = W^T x^T  (per head), bf16 out [H][128][n] ---
  gemm_kernel<<<dim3(2, N_ / 128, H_), dim3(256), 0, stream>>>(
      WgT, xb, D_, D_, D_, nullptr, WhTg, N_, 0, (long)D_ * D_, 0, (long)D_ * N_);
  gemm_kernel<<<dim3(2, T_ / 128, H_), dim3(256), 0, stream>>>(
      WtT, txb, D_, D_, D_, nullptr, WhTt, T_, 0, (long)D_ * D_, 0, (long)D_ * T_);

  // --- attention (k-split partials + combine) ---
  attn_kernel<<<dim3(RBg, H_, Sg), dim3(256), 0, stream>>>(
      WhTg, (const unsigned char*)bitsG, fsAg, fdAg, paccG, pzG, N_, Sg);
  attn_combine_kernel<<<dim3(RBg, H_), dim3(256), 0, stream>>>(paccG, pzG, hcatG, Sg);
  attn_kernel<<<dim3(RBt, H_, St), dim3(256), 0, stream>>>(
      WhTt, (const unsigned char*)bitsT, fsAt, fdAt, paccT, pzT, T_, St);
  attn_combine_kernel<<<dim3(RBt, H_), dim3(256), 0, stream>>>(paccT, pzT, hcatT, St);

  // --- head-concat FC (k-split + reduce): concept fp32, gat_text bf16 transposed ---
  gemm_kernel<<<dim3(N_ / 64, 1, Sf), dim3(256), 0, stream>>>(
      hcatG, fcgT, HD_ / Sf, HD_, HD_, fcPg, nullptr, D_, 3,
      (long)(HD_ / Sf), (long)(HD_ / Sf), (long)N_ * D_);
  reduce_kernel<<<dim3(N_ / 64), dim3(256), 0, stream>>>(
      fcPg, Sf, (long)N_ * D_, fcg_b, conceptF, nullptr, 0, 0);
  gemm_kernel<<<dim3(T_ / 64, 1, Sf), dim3(256), 0, stream>>>(
      hcatT, fctT, HD_ / Sf, HD_, HD_, fcPt, nullptr, D_, 3,
      (long)(HD_ / Sf), (long)(HD_ / Sf), (long)T_ * D_);
  reduce_kernel<<<dim3(T_ / 64), dim3(256), 0, stream>>>(
      fcPt, Sf, (long)T_ * D_, fct_b, nullptr, gatT, T_, 1);

  // --- c_text partials = tfidf^T @ gat_text (k-split Sc) ---
  gemm_kernel<<<dim3(N_ / 64, 1, Sc), dim3(256), 0, stream>>>(
      tfidfT, gatT, T_ / Sc, T_, T_, ctextP, nullptr, D_, 3,
      (long)(T_ / Sc), (long)(T_ / Sc), (long)N_ * D_);

  // --- gated fusion + final linear + relu ---
  fusion_kernel<<<dim3(N_ / 64), dim3(256), 0, stream>>>(conceptF, ctextP, Sc, (long)N_ * D_,
                                                         fusT, fus_b, out);
}